// Round 10
// baseline (210.541 us; speedup 1.0000x reference)
//
#include <hip/hip_runtime.h>
#include <hip/hip_bf16.h>

#define SEQ   2048
#define DIMC  1024
#define NH    16
#define HD    64
#define QKV3  3072
#define NB    2
// 1/sqrt(64) * log2(e), folded into Q so softmax uses exp2 directly
#define SCALE_LOG2E 0.18033688011112042f
// static softmax bias: P = exp2(S - SM_BIAS); |S| <= ~9 for this data, f32-safe for any sane input
#define SM_BIAS 16.0f

typedef __attribute__((ext_vector_type(8)))  short bf16x8;
typedef __attribute__((ext_vector_type(4)))  float f32x4;
typedef __attribute__((ext_vector_type(16))) float f32x16;

__device__ __forceinline__ unsigned short f2bf(float f){
  union { float f; unsigned int u; } v; v.f = f;
  return (unsigned short)((v.u + 0x7fffu + ((v.u >> 16) & 1u)) >> 16);
}
__device__ __forceinline__ float bf2f(unsigned short h){
  union { unsigned int u; float f; } v; v.u = ((unsigned int)h) << 16; return v.f;
}
__device__ __forceinline__ int packbf2(float a, float b){
  __hip_bfloat162 h = __float22bfloat162_rn(make_float2(a, b));  // a -> low16, b -> high16
  int r; __builtin_memcpy(&r, &h, 4); return r;
}
__device__ __forceinline__ void async_lds16(void* lds, const void* g){
  __builtin_amdgcn_global_load_lds(
      (const __attribute__((address_space(1))) void*)g,
      (__attribute__((address_space(3))) void*)lds, 16, 0, 0);
}

// ---------------- prep: f32->bf16 casts (x, Wqkv, Wproj) + RoPE cos/sin table ----------------
__global__ __launch_bounds__(256) void k_prep(const float* __restrict__ x,
                                              const float* __restrict__ wqkv,
                                              const float* __restrict__ wproj,
                                              unsigned short* __restrict__ xb,
                                              unsigned short* __restrict__ wqkvb,
                                              unsigned short* __restrict__ wprojb,
                                              float2* __restrict__ tab){
  const int b = blockIdx.x, tid = threadIdx.x;
  if (b < 8192){
    const float* in; unsigned short* out; int i;
    if (b < 4096)      { in = x;     out = xb;     i = b * 256 + tid; }
    else if (b < 7168) { in = wqkv;  out = wqkvb;  i = (b - 4096) * 256 + tid; }
    else               { in = wproj; out = wprojb; i = (b - 7168) * 256 + tid; }
    const float4 v = ((const float4*)in)[i];
    union { unsigned short s[4]; unsigned long long u; } p;
    p.s[0] = f2bf(v.x); p.s[1] = f2bf(v.y); p.s[2] = f2bf(v.z); p.s[3] = f2bf(v.w);
    *(unsigned long long*)(out + (size_t)i * 4) = p.u;
  } else {
    const int idx = (b - 8192) * 256 + tid;            // 2048*32 = 65536
    const int n = idx >> 5, j = idx & 31;
    const float inv = 1.0f / powf(10000.0f, (float)(2 * j) * (1.0f / 64.0f));
    const float f = (float)n * inv;
    tab[idx] = make_float2(cosf(f), sinf(f));
  }
}

// ---------------- GEMM: C[M,N] = A[M,K] * B[N,K]^T (m97 structure, tile-templated) ----------------
// 4 waves as 2x2; wave covers (BM/2)x(BN/2); frags FM=BM/32 x FN=BN/32 of 16x16.
// T1: XCD-chunked blockIdx swizzle (grid must be a multiple of 8) for per-XCD A-panel L2 residency.
template<int OUT_BF16, int BM, int BN>
__global__ __launch_bounds__(256) void k_gemm(const unsigned short* __restrict__ A,
                                              const unsigned short* __restrict__ Bm,
                                              void* __restrict__ Cp, int M, int N, int K){
  constexpr int FM = BM / 32, FN = BN / 32;
  constexpr int CA = BM / 32, CB = BN / 32;     // staging chunks of 2048 elems
  __shared__ unsigned short As[BM * 64];
  __shared__ unsigned short Bs[BN * 64];
  const int tid = threadIdx.x, wave = tid >> 6, lane = tid & 63;
  // XCD-chunked swizzle: xcd = blk%8 gets contiguous chunk of wg ids
  const int wg = (blockIdx.x & 7) * (gridDim.x >> 3) + (blockIdx.x >> 3);
  const int nbn = N / BN;
  const int bm = wg / nbn, bn = wg % nbn;
  const int m0 = bm * BM, n0 = bn * BN;
  const int wr = wave >> 1, wc = wave & 1;

  f32x4 acc[FM][FN];
#pragma unroll
  for (int i = 0; i < FM; i++)
#pragma unroll
    for (int j = 0; j < FN; j++) acc[i][j] = (f32x4){0.f, 0.f, 0.f, 0.f};

  for (int k0 = 0; k0 < K; k0 += 64){
#pragma unroll
    for (int c = 0; c < CA; c++){
      const int e = c * 2048 + tid * 8;
      const int row = e >> 6, col = e & 63;
      async_lds16(As + c * 2048 + wave * 512, A + (size_t)(m0 + row) * K + k0 + col);
    }
#pragma unroll
    for (int c = 0; c < CB; c++){
      const int e = c * 2048 + tid * 8;
      const int row = e >> 6, col = e & 63;
      async_lds16(Bs + c * 2048 + wave * 512, Bm + (size_t)(n0 + row) * K + k0 + col);
    }
    __syncthreads();
#pragma unroll
    for (int ks = 0; ks < 2; ks++){
      const int kk = ks * 32 + (lane >> 4) * 8;
      bf16x8 af[FM], bfr[FN];
#pragma unroll
      for (int i = 0; i < FM; i++)
        af[i]  = *(const bf16x8*)&As[(wr * (BM / 2) + i * 16 + (lane & 15)) * 64 + kk];
#pragma unroll
      for (int j = 0; j < FN; j++)
        bfr[j] = *(const bf16x8*)&Bs[(wc * (BN / 2) + j * 16 + (lane & 15)) * 64 + kk];
#pragma unroll
      for (int i = 0; i < FM; i++)
#pragma unroll
        for (int j = 0; j < FN; j++)
          acc[i][j] = __builtin_amdgcn_mfma_f32_16x16x32_bf16(af[i], bfr[j], acc[i][j], 0, 0, 0);
    }
    __syncthreads();
  }
#pragma unroll
  for (int i = 0; i < FM; i++)
#pragma unroll
    for (int j = 0; j < FN; j++)
#pragma unroll
      for (int r = 0; r < 4; r++){
        const int row = m0 + wr * (BM / 2) + i * 16 + (lane >> 4) * 4 + r;
        const int col = n0 + wc * (BN / 2) + j * 16 + (lane & 15);
        const float v = acc[i][j][r];
        if constexpr (OUT_BF16) ((unsigned short*)Cp)[(size_t)row * N + col] = f2bf(v);
        else                    ((float*)Cp)[(size_t)row * N + col] = v;
      }
}

// ---------------- post: RoPE q/k + V transpose (merged) ----------------
// Q: linear [B,H,N,D], log2e-scaled.
// K: rows PERMUTED (swap bits 2<->3 of n&31) so QK^T C-regs land in PV fragment order,
//    and cols XOR-swizzled by stored row: Kb[row np][d ^ ((np&7)<<3)].
// V: transposed [B,H,D,N], cols XOR-swizzled within 64-groups by (d&7).
__global__ __launch_bounds__(256) void k_post(const unsigned short* __restrict__ qkv,
                                              const float2* __restrict__ tab,
                                              unsigned short* __restrict__ Qb,
                                              unsigned short* __restrict__ Kswz,
                                              unsigned short* __restrict__ Vt){
  __shared__ unsigned short t[64 * 72];
  if (blockIdx.x < 2048){
    unsigned int idx = blockIdx.x * 256 + threadIdx.x;   // 2*2*16*2048*4 = 524288
    const int j = idx & 3; idx >>= 2;
    const int n = idx & 2047; idx >>= 11;
    const int h = idx & 15; idx >>= 4;
    const int b = idx & 1;
    const int which = idx >> 1;                           // 0=q, 1=k
    const size_t rowbase = ((size_t)(b * SEQ + n)) * QKV3 + which * DIMC + h * HD;
    const bf16x8 lo = *(const bf16x8*)&qkv[rowbase + j * 8];
    const bf16x8 hi = *(const bf16x8*)&qkv[rowbase + 32 + j * 8];
    union { unsigned short s[8]; bf16x8 v; } olo, ohi;
#pragma unroll
    for (int u = 0; u < 8; u++){
      const float2 cs = tab[n * 32 + j * 8 + u];
      const float xl = bf2f((unsigned short)lo[u]), xh = bf2f((unsigned short)hi[u]);
      float yl = xl * cs.x - xh * cs.y;       // d < 32: x*cos - x[d+32]*sin
      float yh = xh * cs.x + xl * cs.y;       // d >= 32: x*cos + x[d-32]*sin
      if (which == 0){ yl *= SCALE_LOG2E; yh *= SCALE_LOG2E; }
      olo.s[u] = f2bf(yl); ohi.s[u] = f2bf(yh);
    }
    if (which == 0){
      const size_t orow = (((size_t)(b * NH + h)) * SEQ + n) * HD;
      *(bf16x8*)&Qb[orow + j * 8]      = olo.v;
      *(bf16x8*)&Qb[orow + 32 + j * 8] = ohi.v;
    } else {
      const int np = (n & ~31) | (n & 0x13) | ((n & 4) << 1) | ((n & 8) >> 1);  // swap23
      const int s = (np & 7) << 3;
      const size_t orow = (((size_t)(b * NH + h)) * SEQ + np) * HD;
      *(bf16x8*)&Kswz[orow + ((j * 8) ^ s)]      = olo.v;
      *(bf16x8*)&Kswz[orow + ((32 + j * 8) ^ s)] = ohi.v;
    }
  } else {
    const int i2 = blockIdx.x - 2048, tid = threadIdx.x;
    const int nt = i2 & 31, h = (i2 >> 5) & 15, b = i2 >> 9;
    const int n0 = nt * 64;
#pragma unroll
    for (int p = 0; p < 2; p++){
      const int e = p * 2048 + tid * 8;
      const int r = e >> 6, c = e & 63;
      *(bf16x8*)&t[r * 72 + c] =
          *(const bf16x8*)&qkv[((size_t)(b * SEQ + n0 + r)) * QKV3 + 2048 + h * 64 + c];
    }
    __syncthreads();
#pragma unroll
    for (int p = 0; p < 2; p++){
      const int e = p * 2048 + tid * 8;
      const int d = e >> 6, nn = e & 63;
      const int sw = (d & 7) << 3;
      union { unsigned short s[8]; bf16x8 v; } o;
#pragma unroll
      for (int q = 0; q < 8; q++) o.s[q] = t[((nn ^ sw) + q) * 72 + d];
      *(bf16x8*)&Vt[(((size_t)(b * NH + h)) * HD + d) * SEQ + n0 + nn] = o.v;
    }
  }
}

// ---------------- Flash attention: BK=128, 4 waves x 32 q-rows, swapped 32x32 MFMA ----------------
// K row-perm makes P fragments lane-local (no exchange). STATIC softmax (exact via shift-invariance).
// LDS 48 KB (K dbuf + V single-buffer) -> 3 blocks/CU. Two barriers/tile:
//   issue V(t), K(t+1) -> QK^T+softmax -> vmcnt(4)+bar (V ready) -> PV -> vmcnt(0)+bar (K ready).
__global__ __launch_bounds__(256) void k_attn(const unsigned short* __restrict__ Q,
                                              const unsigned short* __restrict__ Kg,
                                              const unsigned short* __restrict__ Vg,
                                              unsigned short* __restrict__ AO){
  __shared__ unsigned short Ks[2][128 * 64];   // [buf][stored kv row][d^swz]   16 KB each
  __shared__ unsigned short Vs[64 * 128];      // [d][kv^swz(64-grouped)]       16 KB
  const int tid = threadIdx.x, wave = tid >> 6, lane = tid & 63;
  const int bh = blockIdx.x & 31, qt = blockIdx.x >> 5;   // bh low bits: heads pin to XCDs
  const size_t base = (size_t)bh * (SEQ * HD);
  const int q32 = lane & 31, hi = lane >> 5, hi8 = hi << 3;
  const int sw = (q32 & 7) << 3;
  const int q0w = qt * 128 + wave * 32;

  // Q fragments (B-operand): qf[kc][e] = Q[q0w+q32][kc*16 + hi*8 + e]
  bf16x8 qf[4];
#pragma unroll
  for (int kc = 0; kc < 4; kc++)
    qf[kc] = *(const bf16x8*)&Q[base + (size_t)(q0w + q32) * HD + kc * 16 + hi8];

  f32x16 oacc[2];
#pragma unroll
  for (int md = 0; md < 2; md++)
#pragma unroll
    for (int r = 0; r < 16; r++) oacc[md][r] = 0.f;
  float lrow = 0.f;

  // staging geometry (K: round r covers rows r*32+[0,32); V: round r covers d r*16+[0,16))
  const int krow = wave * 8 + (lane >> 3), kcol = (lane & 7) * 8;
  const int vd   = wave * 4 + (lane >> 4), vcol = (lane & 15) * 8;

  auto stageK = [&](int buf, int kv0){
#pragma unroll
    for (int r = 0; r < 4; r++)
      async_lds16(&Ks[buf][r * 2048 + wave * 512],
                  &Kg[base + (size_t)(kv0 + r * 32 + krow) * HD + kcol]);
  };
  auto stageV = [&](int kv0){
#pragma unroll
    for (int r = 0; r < 4; r++)
      async_lds16(&Vs[r * 2048 + wave * 512],
                  &Vg[base + (size_t)(r * 16 + vd) * SEQ + kv0 + vcol]);
  };

  stageK(0, 0);
  asm volatile("s_waitcnt vmcnt(0)" ::: "memory");
  __syncthreads();

#pragma unroll 1
  for (int t = 0; t < 16; t++){
    const int cur = t & 1;
    // issue order matters: V(t) first (4 loads), then K(t+1) (4 loads) ->
    // vmcnt(4) below retires exactly the V loads (FIFO, oldest-first).
    stageV(t * 128);
    const int tn = (t < 15) ? t + 1 : 15;      // clamp keeps load counts uniform
    stageK(cur ^ 1, tn * 128);

    // ---- QK^T (bias folded into accumulator init): s = S - SM_BIAS
    f32x16 s[4];
#pragma unroll
    for (int k2 = 0; k2 < 4; k2++)
#pragma unroll
      for (int r = 0; r < 16; r++) s[k2][r] = -SM_BIAS;
    __builtin_amdgcn_s_setprio(1);
#pragma unroll
    for (int k2 = 0; k2 < 4; k2++)
#pragma unroll
      for (int kc = 0; kc < 4; kc++){
        const bf16x8 kf = *(const bf16x8*)&Ks[cur][(k2 * 32 + q32) * 64 + ((kc * 16 + hi8) ^ sw)];
        s[k2] = __builtin_amdgcn_mfma_f32_32x32x16_bf16(kf, qf[kc], s[k2], 0, 0, 0);
      }
    __builtin_amdgcn_s_setprio(0);

    // ---- static softmax: P = exp2(s), row-sum (tree + one cross-half shfl)
#pragma unroll
    for (int k2 = 0; k2 < 4; k2++)
#pragma unroll
      for (int r = 0; r < 16; r++)
        s[k2][r] = __builtin_amdgcn_exp2f(s[k2][r]);
    float a16[16];
#pragma unroll
    for (int r = 0; r < 16; r++)
      a16[r] = (s[0][r] + s[1][r]) + (s[2][r] + s[3][r]);
#pragma unroll
    for (int r = 0; r < 8; r++) a16[r] += a16[r + 8];
    float rs = ((a16[0] + a16[1]) + (a16[2] + a16[3])) + ((a16[4] + a16[5]) + (a16[6] + a16[7]));
    rs += __shfl_xor(rs, 32);
    lrow += rs;

    // V(t) ready across all waves: own V loads retired (vmcnt(4)) + barrier joins waves
    asm volatile("s_waitcnt vmcnt(4)" ::: "memory");
    __syncthreads();

    // ---- PV: P fragments are lane-local (row-perm) -> direct pack, no exchange
    __builtin_amdgcn_s_setprio(1);
#pragma unroll
    for (int g2 = 0; g2 < 8; g2++){
      const int k2 = g2 >> 1, off = (g2 & 1) * 8;
      union { int w[4]; bf16x8 v; } pb;
      pb.w[0] = packbf2(s[k2][off + 0], s[k2][off + 1]);
      pb.w[1] = packbf2(s[k2][off + 2], s[k2][off + 3]);
      pb.w[2] = packbf2(s[k2][off + 4], s[k2][off + 5]);
      pb.w[3] = packbf2(s[k2][off + 6], s[k2][off + 7]);
      const int col = g2 * 16 + hi8;
      const int colA = ((col & 63) ^ sw) | (col & 64);
#pragma unroll
      for (int md = 0; md < 2; md++){
        const bf16x8 av = *(const bf16x8*)&Vs[(md * 32 + q32) * 128 + colA];
        oacc[md] = __builtin_amdgcn_mfma_f32_32x32x16_bf16(av, pb.v, oacc[md], 0, 0, 0);
      }
    }
    __builtin_amdgcn_s_setprio(0);

    // K(t+1) landed; all waves past PV so Vs may be overwritten next iter
    asm volatile("s_waitcnt vmcnt(0)" ::: "memory");
    __syncthreads();
  }

  // ---- epilogue: O[q][d] = oacc^T / lrow ; d = md*32 + 8a + 4*hi + b
  const float rl = 1.0f / lrow;
  const int b = bh >> 4, h = bh & 15;
  const size_t obase = ((size_t)(b * SEQ + q0w + q32)) * DIMC + h * HD;
#pragma unroll
  for (int md = 0; md < 2; md++)
#pragma unroll
    for (int a = 0; a < 4; a++){
      const int d0 = md * 32 + a * 8 + hi * 4;
      int2 wv;
      wv.x = packbf2(oacc[md][a * 4 + 0] * rl, oacc[md][a * 4 + 1] * rl);
      wv.y = packbf2(oacc[md][a * 4 + 2] * rl, oacc[md][a * 4 + 3] * rl);
      *(int2*)&AO[obase + d0] = wv;
    }
}

extern "C" void kernel_launch(void* const* d_in, const int* in_sizes, int n_in,
                              void* d_out, int out_size, void* d_ws, size_t ws_size,
                              hipStream_t stream){
  const float* x     = (const float*)d_in[0];
  const float* Wqkv  = (const float*)d_in[1];
  const float* Wproj = (const float*)d_in[2];
  float* out = (float*)d_out;
  char* ws = (char*)d_ws;

  unsigned short* xb     = (unsigned short*)(ws);               //  8,388,608 B
  unsigned short* wqkvb  = (unsigned short*)(ws +  8388608);    //  6,291,456 B
  unsigned short* wprojb = (unsigned short*)(ws + 14680064);    //  2,097,152 B
  unsigned short* qkvb   = (unsigned short*)(ws + 16777216);    // 25,165,824 B
  float2*         tab    = (float2*)        (ws + 41943040);    //    524,288 B
  unsigned short* Qb     = (unsigned short*)(ws + 42467328);    //  8,388,608 B
  unsigned short* Kb     = (unsigned short*)(ws + 50855936);    //  8,388,608 B
  unsigned short* Vtb    = (unsigned short*)(ws + 59244544);    //  8,388,608 B
  unsigned short* AOb    = (unsigned short*)(ws);               // reuse xb (dead after GEMM1)

  // casts + RoPE table
  k_prep<<<8448, 256, 0, stream>>>(x, Wqkv, Wproj, xb, wqkvb, wprojb, tab);
  // QKV projection (128x128 tiles, 768 blocks = 3/CU, XCD-chunked)
  k_gemm<1, 128, 128><<<768, 256, 0, stream>>>(xb, wqkvb, (void*)qkvb, 4096, 3072, 1024);
  // RoPE q / k (row-permuted + swizzled) and V transpose (swizzled), merged
  k_post<<<3072, 256, 0, stream>>>(qkvb, tab, Qb, Kb, Vtb);
  // flash attention (BK=128, exchange-free P, static softmax, 3 blocks/CU)
  k_attn<<<512, 256, 0, stream>>>(Qb, Kb, Vtb, AOb);
  // output projection (64x128 tiles -> 512 blocks = 2/CU, XCD-chunked)
  k_gemm<0, 64, 128><<<512, 256, 0, stream>>>(AOb, wprojb, (void*)out, 4096, 1024, 1024);
}

// Round 11
// 204.039 us; speedup vs baseline: 1.0319x; 1.0319x over previous
//
#include <hip/hip_runtime.h>
#include <hip/hip_bf16.h>

#define SEQ   2048
#define DIMC  1024
#define NH    16
#define HD    64
#define NB    2
// 1/sqrt(64) * log2(e), folded into Q so softmax uses exp2 directly
#define SCALE_LOG2E 0.18033688011112042f
// static softmax bias: P = exp2(S - SM_BIAS); |S| <= ~9 for this data, f32-safe for any sane input
#define SM_BIAS 16.0f

typedef __attribute__((ext_vector_type(8)))  short bf16x8;
typedef __attribute__((ext_vector_type(4)))  float f32x4;
typedef __attribute__((ext_vector_type(16))) float f32x16;

__device__ __forceinline__ unsigned short f2bf(float f){
  union { float f; unsigned int u; } v; v.f = f;
  return (unsigned short)((v.u + 0x7fffu + ((v.u >> 16) & 1u)) >> 16);
}
__device__ __forceinline__ float bf2f(unsigned short h){
  union { unsigned int u; float f; } v; v.u = ((unsigned int)h) << 16; return v.f;
}
__device__ __forceinline__ int packbf2(float a, float b){
  __hip_bfloat162 h = __float22bfloat162_rn(make_float2(a, b));  // a -> low16, b -> high16
  int r; __builtin_memcpy(&r, &h, 4); return r;
}
__device__ __forceinline__ void async_lds16(void* lds, const void* g){
  __builtin_amdgcn_global_load_lds(
      (const __attribute__((address_space(1))) void*)g,
      (__attribute__((address_space(3))) void*)lds, 16, 0, 0);
}

// ---------------- prep: f32->bf16 casts (x, Wqkv, Wproj) + RoPE cos/sin table ----------------
__global__ __launch_bounds__(256) void k_prep(const float* __restrict__ x,
                                              const float* __restrict__ wqkv,
                                              const float* __restrict__ wproj,
                                              unsigned short* __restrict__ xb,
                                              unsigned short* __restrict__ wqkvb,
                                              unsigned short* __restrict__ wprojb,
                                              float2* __restrict__ tab){
  const int b = blockIdx.x, tid = threadIdx.x;
  if (b < 8192){
    const float* in; unsigned short* out; int i;
    if (b < 4096)      { in = x;     out = xb;     i = b * 256 + tid; }
    else if (b < 7168) { in = wqkv;  out = wqkvb;  i = (b - 4096) * 256 + tid; }
    else               { in = wproj; out = wprojb; i = (b - 7168) * 256 + tid; }
    const float4 v = ((const float4*)in)[i];
    union { unsigned short s[4]; unsigned long long u; } p;
    p.s[0] = f2bf(v.x); p.s[1] = f2bf(v.y); p.s[2] = f2bf(v.z); p.s[3] = f2bf(v.w);
    *(unsigned long long*)(out + (size_t)i * 4) = p.u;
  } else {
    const int idx = (b - 8192) * 256 + tid;            // 2048*32 = 65536
    const int n = idx >> 5, j = idx & 31;
    const float inv = 1.0f / powf(10000.0f, (float)(2 * j) * (1.0f / 64.0f));
    const float f = (float)n * inv;
    tab[idx] = make_float2(cosf(f), sinf(f));
  }
}

// ---------------- QKV GEMM with FUSED RoPE epilogue ----------------
// C[4096,3072] = xb * Wqkv^T, 128x128 tiles, BK=64, 4 waves 2x2 (m97 structure).
// BN=128 => each wave's 64-col span is exactly ONE head; RoPE pair d<->d^32 is
// acc[i][j] <-> acc[i][j^2] (same lane). Epilogue writes:
//   bn 0..7  (q): rope + *SCALE_LOG2E -> Qb[b,h,n,d]
//   bn 8..15 (k): rope + row-perm swap23(n&31) + col ^((np&7)<<3) -> Kswz[b,h,np,dsw]
//   bn 16..23(v): plain bf16 rows -> vbuf[n][1024] (k_vt transposes later)
__global__ __launch_bounds__(256) void k_gemmqkv(const unsigned short* __restrict__ A,
                                                 const unsigned short* __restrict__ Bm,
                                                 const float2* __restrict__ tab,
                                                 unsigned short* __restrict__ Qb,
                                                 unsigned short* __restrict__ Kswz,
                                                 unsigned short* __restrict__ vbuf){
  constexpr int K = 1024, N = 3072;
  __shared__ unsigned short As[128 * 64];
  __shared__ unsigned short Bs[128 * 64];
  const int tid = threadIdx.x, wave = tid >> 6, lane = tid & 63;
  const int bm = blockIdx.x / 24, bn = blockIdx.x % 24;
  const int m0 = bm << 7, n0 = bn << 7;
  const int wr = wave >> 1, wc = wave & 1;

  f32x4 acc[4][4];
#pragma unroll
  for (int i = 0; i < 4; i++)
#pragma unroll
    for (int j = 0; j < 4; j++) acc[i][j] = (f32x4){0.f, 0.f, 0.f, 0.f};

  for (int k0 = 0; k0 < K; k0 += 64){
#pragma unroll
    for (int c = 0; c < 4; c++){
      const int e = c * 2048 + tid * 8;
      const int row = e >> 6, col = e & 63;
      async_lds16(As + c * 2048 + wave * 512, A + (size_t)(m0 + row) * K + k0 + col);
      async_lds16(Bs + c * 2048 + wave * 512, Bm + (size_t)(n0 + row) * K + k0 + col);
    }
    __syncthreads();
#pragma unroll
    for (int ks = 0; ks < 2; ks++){
      const int kk = ks * 32 + (lane >> 4) * 8;
      bf16x8 af[4], bfr[4];
#pragma unroll
      for (int i = 0; i < 4; i++){
        af[i]  = *(const bf16x8*)&As[(wr * 64 + i * 16 + (lane & 15)) * 64 + kk];
        bfr[i] = *(const bf16x8*)&Bs[(wc * 64 + i * 16 + (lane & 15)) * 64 + kk];
      }
#pragma unroll
      for (int i = 0; i < 4; i++)
#pragma unroll
        for (int j = 0; j < 4; j++)
          acc[i][j] = __builtin_amdgcn_mfma_f32_16x16x32_bf16(af[i], bfr[j], acc[i][j], 0, 0, 0);
    }
    __syncthreads();
  }

  const int l15 = lane & 15;
  const int which = bn >> 3;                       // 0=q, 1=k, 2=v
  if (which == 2){
    // V: plain rows into vbuf[4096][1024]
#pragma unroll
    for (int i = 0; i < 4; i++)
#pragma unroll
      for (int j = 0; j < 4; j++)
#pragma unroll
        for (int r = 0; r < 4; r++){
          const int row = m0 + wr * 64 + i * 16 + (lane >> 4) * 4 + r;
          const int col = (bn & 7) * 128 + wc * 64 + j * 16 + l15;
          vbuf[(size_t)row * 1024 + col] = f2bf(acc[i][j][r]);
        }
  } else {
    const int h = (bn & 7) * 2 + wc;               // wave's head
#pragma unroll
    for (int i = 0; i < 4; i++)
#pragma unroll
      for (int r = 0; r < 4; r++){
        const int row = m0 + wr * 64 + i * 16 + (lane >> 4) * 4 + r;
        const int nn = row & 2047, b = row >> 11;
        const float2 cs0 = tab[nn * 32 + l15];          // d&31 = l15      (j=0,2)
        const float2 cs1 = tab[nn * 32 + 16 + l15];     // d&31 = 16+l15   (j=1,3)
        const float x0 = acc[i][0][r], x1 = acc[i][1][r];
        const float x2 = acc[i][2][r], x3 = acc[i][3][r];
        const float y0 = x0 * cs0.x - x2 * cs0.y;       // d = l15        (<32)
        const float y1 = x1 * cs1.x - x3 * cs1.y;       // d = 16+l15     (<32)
        const float y2 = x2 * cs0.x + x0 * cs0.y;       // d = 32+l15
        const float y3 = x3 * cs1.x + x1 * cs1.y;       // d = 48+l15
        if (which == 0){
          const size_t orow = ((size_t)(b * NH + h) * SEQ + nn) * HD;
          Qb[orow + l15]      = f2bf(y0 * SCALE_LOG2E);
          Qb[orow + 16 + l15] = f2bf(y1 * SCALE_LOG2E);
          Qb[orow + 32 + l15] = f2bf(y2 * SCALE_LOG2E);
          Qb[orow + 48 + l15] = f2bf(y3 * SCALE_LOG2E);
        } else {
          const int np = (nn & ~31) | (nn & 0x13) | ((nn & 4) << 1) | ((nn & 8) >> 1); // swap23
          const int s = (np & 7) << 3;
          const size_t orow = ((size_t)(b * NH + h) * SEQ + np) * HD;
          Kswz[orow + (l15 ^ s)]        = f2bf(y0);
          Kswz[orow + ((16 + l15) ^ s)] = f2bf(y1);
          Kswz[orow + ((32 + l15) ^ s)] = f2bf(y2);
          Kswz[orow + ((48 + l15) ^ s)] = f2bf(y3);
        }
      }
  }
}

// ---------------- GEMM (proj): C[M,N] = A[M,K] * B[N,K]^T, tile-templated, no swizzle ----------
template<int OUT_BF16, int BM, int BN>
__global__ __launch_bounds__(256) void k_gemm(const unsigned short* __restrict__ A,
                                              const unsigned short* __restrict__ Bm,
                                              void* __restrict__ Cp, int M, int N, int K){
  constexpr int FM = BM / 32, FN = BN / 32;
  constexpr int CA = BM / 32, CB = BN / 32;
  __shared__ unsigned short As[BM * 64];
  __shared__ unsigned short Bs[BN * 64];
  const int tid = threadIdx.x, wave = tid >> 6, lane = tid & 63;
  const int nbn = N / BN;
  const int bm = blockIdx.x / nbn, bn = blockIdx.x % nbn;
  const int m0 = bm * BM, n0 = bn * BN;
  const int wr = wave >> 1, wc = wave & 1;

  f32x4 acc[FM][FN];
#pragma unroll
  for (int i = 0; i < FM; i++)
#pragma unroll
    for (int j = 0; j < FN; j++) acc[i][j] = (f32x4){0.f, 0.f, 0.f, 0.f};

  for (int k0 = 0; k0 < K; k0 += 64){
#pragma unroll
    for (int c = 0; c < CA; c++){
      const int e = c * 2048 + tid * 8;
      const int row = e >> 6, col = e & 63;
      async_lds16(As + c * 2048 + wave * 512, A + (size_t)(m0 + row) * K + k0 + col);
    }
#pragma unroll
    for (int c = 0; c < CB; c++){
      const int e = c * 2048 + tid * 8;
      const int row = e >> 6, col = e & 63;
      async_lds16(Bs + c * 2048 + wave * 512, Bm + (size_t)(n0 + row) * K + k0 + col);
    }
    __syncthreads();
#pragma unroll
    for (int ks = 0; ks < 2; ks++){
      const int kk = ks * 32 + (lane >> 4) * 8;
      bf16x8 af[FM], bfr[FN];
#pragma unroll
      for (int i = 0; i < FM; i++)
        af[i]  = *(const bf16x8*)&As[(wr * (BM / 2) + i * 16 + (lane & 15)) * 64 + kk];
#pragma unroll
      for (int j = 0; j < FN; j++)
        bfr[j] = *(const bf16x8*)&Bs[(wc * (BN / 2) + j * 16 + (lane & 15)) * 64 + kk];
#pragma unroll
      for (int i = 0; i < FM; i++)
#pragma unroll
        for (int j = 0; j < FN; j++)
          acc[i][j] = __builtin_amdgcn_mfma_f32_16x16x32_bf16(af[i], bfr[j], acc[i][j], 0, 0, 0);
    }
    __syncthreads();
  }
#pragma unroll
  for (int i = 0; i < FM; i++)
#pragma unroll
    for (int j = 0; j < FN; j++)
#pragma unroll
      for (int r = 0; r < 4; r++){
        const int row = m0 + wr * (BM / 2) + i * 16 + (lane >> 4) * 4 + r;
        const int col = n0 + wc * (BN / 2) + j * 16 + (lane & 15);
        const float v = acc[i][j][r];
        if constexpr (OUT_BF16) ((unsigned short*)Cp)[(size_t)row * N + col] = f2bf(v);
        else                    ((float*)Cp)[(size_t)row * N + col] = v;
      }
}

// ---------------- V transpose: vbuf[n][1024] -> Vtswz[B,H,D,N], XOR-swizzled 64-col groups ------
// Vtswz[d][n0 + c] = V[n0 + (c ^ ((d&7)<<3))][d]
__global__ __launch_bounds__(256) void k_vt(const unsigned short* __restrict__ vbuf,
                                            unsigned short* __restrict__ Vt){
  __shared__ unsigned short t[64 * 72];
  const int tid = threadIdx.x;
  const int nt = blockIdx.x & 31, h = (blockIdx.x >> 5) & 15, b = blockIdx.x >> 9;
  const int n0 = nt * 64;
#pragma unroll
  for (int p = 0; p < 2; p++){
    const int e = p * 2048 + tid * 8;
    const int r = e >> 6, c = e & 63;
    *(bf16x8*)&t[r * 72 + c] =
        *(const bf16x8*)&vbuf[((size_t)(b * SEQ + n0 + r)) * 1024 + h * 64 + c];
  }
  __syncthreads();
#pragma unroll
  for (int p = 0; p < 2; p++){
    const int e = p * 2048 + tid * 8;
    const int d = e >> 6, nn = e & 63;
    const int sw = (d & 7) << 3;
    union { unsigned short s[8]; bf16x8 v; } o;
#pragma unroll
    for (int q = 0; q < 8; q++) o.s[q] = t[((nn ^ sw) + q) * 72 + d];
    *(bf16x8*)&Vt[(((size_t)(b * NH + h)) * HD + d) * SEQ + n0 + nn] = o.v;
  }
}

// ---------------- Flash attention: BK=128, 4 waves x 32 q-rows, swapped 32x32 MFMA ----------------
// R9 schedule (measured best): K+V double-buffered 64KB, stage(t+1) at top, one
// vmcnt(0)+barrier per tile. K row-perm => lane-local P; STATIC softmax (exact).
__global__ __launch_bounds__(256) void k_attn(const unsigned short* __restrict__ Q,
                                              const unsigned short* __restrict__ Kg,
                                              const unsigned short* __restrict__ Vg,
                                              unsigned short* __restrict__ AO){
  __shared__ unsigned short Ks[2][128 * 64];   // [buf][stored kv row][d^swz]
  __shared__ unsigned short Vs[2][64 * 128];   // [buf][d][kv^swz(64-grouped)]
  const int tid = threadIdx.x, wave = tid >> 6, lane = tid & 63;
  const int bh = blockIdx.x & 31, qt = blockIdx.x >> 5;   // bh low bits: heads pin to XCDs
  const size_t base = (size_t)bh * (SEQ * HD);
  const int q32 = lane & 31, hi = lane >> 5, hi8 = hi << 3;
  const int sw = (q32 & 7) << 3;
  const int q0w = qt * 128 + wave * 32;

  bf16x8 qf[4];
#pragma unroll
  for (int kc = 0; kc < 4; kc++)
    qf[kc] = *(const bf16x8*)&Q[base + (size_t)(q0w + q32) * HD + kc * 16 + hi8];

  f32x16 oacc[2];
#pragma unroll
  for (int md = 0; md < 2; md++)
#pragma unroll
    for (int r = 0; r < 16; r++) oacc[md][r] = 0.f;
  float lrow = 0.f;

  const int krow = wave * 8 + (lane >> 3), kcol = (lane & 7) * 8;
  const int vd   = wave * 4 + (lane >> 4), vcol = (lane & 15) * 8;

  auto stage = [&](int buf, int kv0){
#pragma unroll
    for (int r = 0; r < 4; r++)
      async_lds16(&Ks[buf][r * 2048 + wave * 512],
                  &Kg[base + (size_t)(kv0 + r * 32 + krow) * HD + kcol]);
#pragma unroll
    for (int r = 0; r < 4; r++)
      async_lds16(&Vs[buf][r * 2048 + wave * 512],
                  &Vg[base + (size_t)(r * 16 + vd) * SEQ + kv0 + vcol]);
  };

  stage(0, 0);
  asm volatile("s_waitcnt vmcnt(0)" ::: "memory");
  __syncthreads();

#pragma unroll 1
  for (int t = 0; t < 16; t++){
    const int cur = t & 1;
    if (t < 15) stage(cur ^ 1, (t + 1) * 128);   // overlaps with compute below

    // ---- QK^T (bias folded into accumulator init): s = S - SM_BIAS
    f32x16 s[4];
#pragma unroll
    for (int k2 = 0; k2 < 4; k2++)
#pragma unroll
      for (int r = 0; r < 16; r++) s[k2][r] = -SM_BIAS;
    __builtin_amdgcn_s_setprio(1);
#pragma unroll
    for (int k2 = 0; k2 < 4; k2++)
#pragma unroll
      for (int kc = 0; kc < 4; kc++){
        const bf16x8 kf = *(const bf16x8*)&Ks[cur][(k2 * 32 + q32) * 64 + ((kc * 16 + hi8) ^ sw)];
        s[k2] = __builtin_amdgcn_mfma_f32_32x32x16_bf16(kf, qf[kc], s[k2], 0, 0, 0);
      }
    __builtin_amdgcn_s_setprio(0);

    // ---- static softmax: P = exp2(s), row-sum (tree + one cross-half shfl)
#pragma unroll
    for (int k2 = 0; k2 < 4; k2++)
#pragma unroll
      for (int r = 0; r < 16; r++)
        s[k2][r] = __builtin_amdgcn_exp2f(s[k2][r]);
    float a16[16];
#pragma unroll
    for (int r = 0; r < 16; r++)
      a16[r] = (s[0][r] + s[1][r]) + (s[2][r] + s[3][r]);
#pragma unroll
    for (int r = 0; r < 8; r++) a16[r] += a16[r + 8];
    float rs = ((a16[0] + a16[1]) + (a16[2] + a16[3])) + ((a16[4] + a16[5]) + (a16[6] + a16[7]));
    rs += __shfl_xor(rs, 32);
    lrow += rs;

    // ---- PV: P fragments are lane-local (row-perm) -> direct pack, no exchange
    __builtin_amdgcn_s_setprio(1);
#pragma unroll
    for (int g2 = 0; g2 < 8; g2++){
      const int k2 = g2 >> 1, off = (g2 & 1) * 8;
      union { int w[4]; bf16x8 v; } pb;
      pb.w[0] = packbf2(s[k2][off + 0], s[k2][off + 1]);
      pb.w[1] = packbf2(s[k2][off + 2], s[k2][off + 3]);
      pb.w[2] = packbf2(s[k2][off + 4], s[k2][off + 5]);
      pb.w[3] = packbf2(s[k2][off + 6], s[k2][off + 7]);
      const int col = g2 * 16 + hi8;
      const int colA = ((col & 63) ^ sw) | (col & 64);
#pragma unroll
      for (int md = 0; md < 2; md++){
        const bf16x8 av = *(const bf16x8*)&Vs[cur][(md * 32 + q32) * 128 + colA];
        oacc[md] = __builtin_amdgcn_mfma_f32_32x32x16_bf16(av, pb.v, oacc[md], 0, 0, 0);
      }
    }
    __builtin_amdgcn_s_setprio(0);

    asm volatile("s_waitcnt vmcnt(0)" ::: "memory");
    __syncthreads();
  }

  // ---- epilogue: O[q][d] = oacc^T / lrow ; d = md*32 + 8a + 4*hi + b
  const float rl = 1.0f / lrow;
  const int b = bh >> 4, h = bh & 15;
  const size_t obase = ((size_t)(b * SEQ + q0w + q32)) * DIMC + h * HD;
#pragma unroll
  for (int md = 0; md < 2; md++)
#pragma unroll
    for (int a = 0; a < 4; a++){
      const int d0 = md * 32 + a * 8 + hi * 4;
      int2 wv;
      wv.x = packbf2(oacc[md][a * 4 + 0] * rl, oacc[md][a * 4 + 1] * rl);
      wv.y = packbf2(oacc[md][a * 4 + 2] * rl, oacc[md][a * 4 + 3] * rl);
      *(int2*)&AO[obase + d0] = wv;
    }
}

extern "C" void kernel_launch(void* const* d_in, const int* in_sizes, int n_in,
                              void* d_out, int out_size, void* d_ws, size_t ws_size,
                              hipStream_t stream){
  const float* x     = (const float*)d_in[0];
  const float* Wqkv  = (const float*)d_in[1];
  const float* Wproj = (const float*)d_in[2];
  float* out = (float*)d_out;
  char* ws = (char*)d_ws;

  unsigned short* xb     = (unsigned short*)(ws);               //  8,388,608 B
  unsigned short* wqkvb  = (unsigned short*)(ws +  8388608);    //  6,291,456 B
  unsigned short* wprojb = (unsigned short*)(ws + 14680064);    //  2,097,152 B
  float2*         tab    = (float2*)        (ws + 16777216);    //    524,288 B
  unsigned short* Qb     = (unsigned short*)(ws + 17301504);    //  8,388,608 B
  unsigned short* Kb     = (unsigned short*)(ws + 25690112);    //  8,388,608 B
  unsigned short* vbuf   = (unsigned short*)(ws + 34078720);    //  8,388,608 B
  unsigned short* Vtb    = (unsigned short*)(ws + 42467328);    //  8,388,608 B
  unsigned short* AOb    = (unsigned short*)(ws);               // reuse xb (dead after gemmqkv)

  // casts + RoPE table
  k_prep<<<8448, 256, 0, stream>>>(x, Wqkv, Wproj, xb, wqkvb, wprojb, tab);
  // QKV projection with fused RoPE epilogue (writes Qb/Kswz/vbuf directly)
  k_gemmqkv<<<768, 256, 0, stream>>>(xb, wqkvb, tab, Qb, Kb, vbuf);
  // V transpose (swizzled)
  k_vt<<<1024, 256, 0, stream>>>(vbuf, Vtb);
  // flash attention (R9 schedule: 64KB dbuf, one barrier pair/tile, static softmax)
  k_attn<<<512, 256, 0, stream>>>(Qb, Kb, Vtb, AOb);
  // output projection (64x128 tiles -> 512 blocks)
  k_gemm<0, 64, 128><<<512, 256, 0, stream>>>(AOb, wprojb, (void*)out, 4096, 1024, 1024);
}